// Round 14
// baseline (557.008 us; speedup 1.0000x reference)
//
#include <hip/hip_runtime.h>
#include <stdint.h>

typedef __attribute__((ext_vector_type(4))) float f32x4;
typedef __attribute__((ext_vector_type(8))) short s16x8;

#define MFMA16(A, B, C) __builtin_amdgcn_mfma_f32_16x16x32_bf16(A, B, C, 0, 0, 0)
#define WAIT_VM(N) asm volatile("s_waitcnt vmcnt(" #N ")" ::: "memory")
#define WAIT_LGKM() asm volatile("s_waitcnt lgkmcnt(0)" ::: "memory")
#define BAR() __builtin_amdgcn_s_barrier()
#define SCHED_FENCE() __builtin_amdgcn_sched_barrier(0)
#define SP1() __builtin_amdgcn_s_setprio(1)
#define SP0() __builtin_amdgcn_s_setprio(0)

__device__ __forceinline__ unsigned short f2bf(float x) {
  union { float f; unsigned u; } v; v.f = x;
  return (unsigned short)((v.u + 0x7fffu + ((v.u >> 16) & 1u)) >> 16);
}

// ---------------- cast f32 -> bf16, 4 elems/thread ----------------
__global__ void k_cast_bf16(const float* __restrict__ in, unsigned short* __restrict__ out, int n4) {
  int i = blockIdx.x * blockDim.x + threadIdx.x;
  const int stride = gridDim.x * blockDim.x;
  for (; i < n4; i += stride) {
    const float4 v = ((const float4*)in)[i];
    ushort4 o;
    o.x = f2bf(v.x); o.y = f2bf(v.y); o.z = f2bf(v.z); o.w = f2bf(v.w);
    ((ushort4*)out)[i] = o;
  }
}

// ---------------- exc [16384][28] -> excT bf16 [32][16384] (rows 28..31 = 0) + b[28] ----------------
__global__ void k_excT(const float* __restrict__ exc, unsigned short* __restrict__ excT,
                       float* __restrict__ bvec) {
  const int c = blockIdx.x;        // 0..31
  const int tid = threadIdx.x;     // 256
  float sum = 0.f;
  for (int j = tid; j < 16384; j += 256) {
    const float v = (c < 28) ? exc[(size_t)j * 28 + c] : 0.f;
    excT[(size_t)c * 16384 + j] = f2bf(v);
    sum += v;
  }
  #pragma unroll
  for (int o = 32; o; o >>= 1) sum += __shfl_down(sum, o, 64);
  __shared__ float wsum[4];
  if ((tid & 63) == 0) wsum[tid >> 6] = sum;
  __syncthreads();
  if (tid == 0 && c < 28) bvec[c] = fmaxf(wsum[0] + wsum[1] + wsum[2] + wsum[3], 1.0f);
}

// ================= k_proj (unchanged working engine) =================
__device__ __forceinline__ void stage_a(const unsigned short* __restrict__ src, int ld,
                                        unsigned short* smem, int dsoff, int w, int offsrc) {
  #pragma unroll
  for (int c = 0; c < 4; ++c)
    __builtin_amdgcn_global_load_lds(
        (const __attribute__((address_space(1))) unsigned int*)(src + offsrc + c * 64 * ld),
        (__attribute__((address_space(3))) unsigned int*)(smem + dsoff + c * 4096 + w * 512),
        16, 0, 0);
}
__device__ __forceinline__ void stage_b(const unsigned short* __restrict__ src, int ld,
                                        unsigned short* smem, int dsoff, int w, int offsrc) {
  #pragma unroll
  for (int c = 0; c < 2; ++c)
    __builtin_amdgcn_global_load_lds(
        (const __attribute__((address_space(1))) unsigned int*)(src + offsrc + c * 64 * ld),
        (__attribute__((address_space(3))) unsigned int*)(smem + dsoff + c * 4096 + w * 512),
        16, 0, 0);
}

__device__ __forceinline__ void mma_step_p(const unsigned short* smem, int ao, int bo,
                                           int wr, int wc, int r, int q, f32x4 acc[8][2]) {
  const int rx = r & 7;
  #pragma unroll
  for (int ks = 0; ks < 2; ++ks) {
    const int sb = ((ks * 4 + q) ^ rx) << 3;
    s16x8 bf[2];
    #pragma unroll
    for (int j = 0; j < 2; ++j)
      bf[j] = *(const s16x8*)(smem + bo + (wc * 32 + j * 16 + r) * 64 + sb);
    #pragma unroll
    for (int i = 0; i < 8; ++i) {
      const s16x8 af = *(const s16x8*)(smem + ao + (wr * 128 + i * 16 + r) * 64 + sb);
      #pragma unroll
      for (int j = 0; j < 2; ++j)
        acc[i][j] = MFMA16(af, bf[j], acc[i][j]);
    }
  }
}

#define PA0 0
#define PB0 16384
#define PA1 24576
#define PB1 40960

__global__ __launch_bounds__(512, 2) void k_proj(const unsigned short* __restrict__ featbf,
                                                 const unsigned short* __restrict__ exbf,
                                                 const unsigned short* __restrict__ gwbf,
                                                 const float* __restrict__ gb,
                                                 float* __restrict__ fall) {
  __shared__ __align__(16) unsigned short smem[49152];  // 96 KB
  const int tid = threadIdx.x, w = tid >> 6, lane = tid & 63;
  const int wr = w >> 2, wc = w & 3, r = lane & 15, q = lane >> 4;
  const int offsrc = (w * 8 + (lane >> 3)) * 1024 + (((lane & 7) ^ (lane >> 3)) << 3);
  const int m0 = blockIdx.x * 256;
  const int n0 = blockIdx.y * 128;
  const unsigned short* Asrc = (m0 < 8192) ? (featbf + (size_t)m0 * 1024)
                                           : (exbf + (size_t)(m0 - 8192) * 1024);
  const unsigned short* Bsrc = gwbf + (size_t)n0 * 1024;
  f32x4 acc[8][2];
  #pragma unroll
  for (int i = 0; i < 8; ++i)
    #pragma unroll
    for (int j = 0; j < 2; ++j) acc[i][j] = {0.f, 0.f, 0.f, 0.f};

  stage_a(Asrc, 1024, smem, PA0, w, offsrc);
  stage_b(Bsrc, 1024, smem, PB0, w, offsrc);
  for (int t = 0; t < 15; ++t) {
    const int na = ((t + 1) & 1) ? PA1 : PA0, nbb = ((t + 1) & 1) ? PB1 : PB0;
    stage_a(Asrc + (t + 1) * 64, 1024, smem, na, w, offsrc);
    stage_b(Bsrc + (t + 1) * 64, 1024, smem, nbb, w, offsrc);
    WAIT_VM(6);
    BAR();
    mma_step_p(smem, (t & 1) ? PA1 : PA0, (t & 1) ? PB1 : PB0, wr, wc, r, q, acc);
    WAIT_LGKM();
    BAR();
  }
  WAIT_VM(0);
  BAR();
  mma_step_p(smem, PA1, PB1, wr, wc, r, q, acc);

  #pragma unroll
  for (int j = 0; j < 2; ++j) {
    const int col = n0 + wc * 32 + j * 16 + r;
    const float bias = gb[col];
    #pragma unroll
    for (int i = 0; i < 8; ++i) {
      const int row0 = m0 + wr * 128 + i * 16 + q * 4;
      #pragma unroll
      for (int t = 0; t < 4; ++t)
        fall[(size_t)(row0 + t) * 512 + col] = acc[i][j][t] + bias;
    }
  }
}

// ---------------- normalize rows of f_all (512) -> bf16 fn_all ----------------
__global__ __launch_bounds__(256) void k_norm(const float* __restrict__ fall,
                                              unsigned short* __restrict__ fn) {
  const int row = blockIdx.x * 4 + (threadIdx.x >> 6);
  const int lane = threadIdx.x & 63;
  const float4* p = (const float4*)(fall + (size_t)row * 512) + lane * 2;
  const float4 v0 = p[0], v1 = p[1];
  float ss = v0.x * v0.x + v0.y * v0.y + v0.z * v0.z + v0.w * v0.w
           + v1.x * v1.x + v1.y * v1.y + v1.z * v1.z + v1.w * v1.w;
  #pragma unroll
  for (int o = 32; o; o >>= 1) ss += __shfl_xor(ss, o, 64);
  const float sc = 1.0f / fmaxf(sqrtf(ss), 1e-12f);
  ushort4 o0, o1;
  o0.x = f2bf(v0.x * sc); o0.y = f2bf(v0.y * sc); o0.z = f2bf(v0.z * sc); o0.w = f2bf(v0.w * sc);
  o1.x = f2bf(v1.x * sc); o1.y = f2bf(v1.y * sc); o1.z = f2bf(v1.z * sc); o1.w = f2bf(v1.w * sc);
  ushort4* qo = (ushort4*)(fn + (size_t)row * 512) + lane * 2;
  qo[0] = o0; qo[1] = o1;
}

// ========== k_fused: 1024 threads / 16 waves (4M x 4N), 64x64 per wave, BK=32 ==========
// LDS (shorts): buf0 @0, buf1 @16384 (each: A[256][32] @0 | B[256][32] @8192),
// excT [32][256] @32768, aL [128][256] @40960. Total 73728 shorts = 144 KB.
// Staging swizzle: LDS[row][blk] = G[row][blk ^ ((row>>1)&3)]; read koff = (q^((r>>1)&3))*8.
#define BUF 16384
#define EXLo 32768
#define ALo 40960

// stage one 256x32 panel: 1024 threads x 16 B; row = tid>>2, blk = tid&3; dest linear.
__device__ __forceinline__ void stage_t(const unsigned short* __restrict__ src,
                                        unsigned short* smem, int dsoff, int tid, int soff) {
  __builtin_amdgcn_global_load_lds(
      (const __attribute__((address_space(1))) unsigned int*)(src + soff),
      (__attribute__((address_space(3))) unsigned int*)(smem + dsoff + tid * 8), 16, 0, 0);
}

// stage excT slice [32][256] -> EXLo in ONE gload (1024 threads x 16 B), swizzled
__device__ __forceinline__ void stage_exc(const unsigned short* __restrict__ excTg, int c0,
                                          unsigned short* smem, int tid) {
  const int row = tid >> 5, b = tid & 31;
  const int sb = ((b & 24) | ((b ^ (row & 7)) & 7)) << 3;
  __builtin_amdgcn_global_load_lds(
      (const __attribute__((address_space(1))) unsigned int*)(excTg + (size_t)row * 16384 + c0 + sb),
      (__attribute__((address_space(3))) unsigned int*)(smem + EXLo + tid * 8), 16, 0, 0);
}

// one K-tile (BK=32): 8 ds_read_b128 + 16 MFMA per wave
__device__ __forceinline__ void ktile(const unsigned short* smem, int bufR,
                                      int wr, int wc, int r, int koff, f32x4 acc[4][4]) {
  const unsigned short* Bb = smem + bufR + 8192 + (wc * 64 + r) * 32 + koff;
  s16x8 bf[4];
  #pragma unroll
  for (int fj = 0; fj < 4; ++fj)
    bf[fj] = *(const s16x8*)(Bb + fj * 512);           // +16 rows = 512 shorts
  #pragma unroll
  for (int fi = 0; fi < 4; ++fi) {
    const s16x8 af = *(const s16x8*)(smem + bufR + (wr * 64 + fi * 16 + r) * 32 + koff);
    #pragma unroll
    for (int fj = 0; fj < 4; ++fj)
      acc[fi][fj] = MFMA16(af, bf[fj], acc[fi][fj]);
  }
}

__global__ __launch_bounds__(1024, 4) void k_fused(const unsigned short* __restrict__ fnall,
                                                   const unsigned short* __restrict__ excT,
                                                   float* __restrict__ partial) {
  __shared__ __align__(16) unsigned short smem[73728];  // 144 KB
  const int tid = threadIdx.x, w = tid >> 6, lane = tid & 63;
  const int wr = w >> 2, wc = w & 3, r = lane & 15, q = lane >> 4, rx = r & 7;
  const int koff = (q ^ ((r >> 1) & 3)) << 3;
  const int soff = (tid >> 2) * 512 + (((tid & 3) ^ ((tid >> 3) & 3)) << 3);
  const int r0 = blockIdx.x * 256;     // 32 M-tiles
  const int nchunk = blockIdx.y;       // 16 chunks x 4 j-tiles of 256
  const unsigned short* Abase = fnall + (size_t)r0 * 512;
  const unsigned short* Ebase = fnall + (size_t)8192 * 512;
  unsigned short* aLb = smem + ALo;

  f32x4 acc[4][4];                     // [fi][fj] -> 64 regs
  f32x4 eacc[2];                       // per-pass echo frag (16 rows x 16 cls)
  eacc[0] = {0.f, 0.f, 0.f, 0.f};
  eacc[1] = {0.f, 0.f, 0.f, 0.f};

  // prologue: jt0 tile0 -> buf0
  {
    const unsigned short* Bp = Ebase + (size_t)(nchunk * 4) * 256 * 512;
    stage_t(Bp, smem, 8192, tid, soff);
    stage_t(Abase, smem, 0, tid, soff);
  }

  for (int jt = 0; jt < 4; ++jt) {
    const int c0 = (nchunk * 4 + jt) * 256;
    const unsigned short* Bsrc = Ebase + (size_t)c0 * 512;
    #pragma unroll
    for (int fi = 0; fi < 4; ++fi)
      #pragma unroll
      for (int fj = 0; fj < 4; ++fj) acc[fi][fj] = {0.f, 0.f, 0.f, 0.f};

    for (int tk = 0; tk < 16; ++tk) {
      const int bufR = (tk & 1) * BUF, bufW = bufR ^ BUF;
      // single per-tile sync: own ds reads drained; ALL waves' tile-t panels landed
      SCHED_FENCE(); WAIT_LGKM(); WAIT_VM(0); BAR(); SCHED_FENCE();
      if (tk < 15) {
        stage_t(Bsrc + (tk + 1) * 32, smem, bufW + 8192, tid, soff);
        stage_t(Abase + (tk + 1) * 32, smem, bufW + 0, tid, soff);
      } else {
        stage_exc(excT, c0, smem, tid);          // exc first (echo waits vm(2))
        if (jt < 3) {
          stage_t(Ebase + (size_t)(c0 + 256) * 512, smem, bufW + 8192, tid, soff);
          stage_t(Abase, smem, bufW + 0, tid, soff);
        }
      }
      SP1(); ktile(smem, bufR, wr, wc, r, koff, acc); SP0();
    }

    // ---- echo: a = s^3 via aL; 2 row-half passes; wave w: rows (w&7)*16, cls half w>>3
    SCHED_FENCE(); WAIT_LGKM();
    if (jt < 3) { WAIT_VM(2); } else { WAIT_VM(0); }  // exc landed; next-jt panels keep flying
    BAR(); SCHED_FENCE();
    const int hmine = wr >> 1;                       // pass in which this wave cube-writes
    #pragma unroll
    for (int h = 0; h < 2; ++h) {
      if (hmine == h) {
        #pragma unroll
        for (int fi = 0; fi < 4; ++fi)
          #pragma unroll
          for (int fj = 0; fj < 4; ++fj) {
            const int col = wc * 64 + fj * 16 + r;
            const int cb = col >> 3, cl = col & 7;
            #pragma unroll
            for (int t2 = 0; t2 < 4; ++t2) {
              const int rowl = (wr & 1) * 64 + fi * 16 + q * 4 + t2;
              const float v = acc[fi][fj][t2];
              aLb[rowl * 256 + ((((cb & 24) | ((cb ^ (rowl & 7)) & 7)) << 3) | cl)] = f2bf(v * v * v);
            }
          }
      }
      SCHED_FENCE(); WAIT_LGKM(); BAR(); SCHED_FENCE();
      // echo MFMA (16x16x32): rows (w&7)*16..+15 of this half, classes (w>>3)*16..+15; K=256
      {
        const int rE = (w & 7) * 16 + r;
        const int re8 = rE & 7;
        const int njo = (w >> 3) * 16;
        #pragma unroll
        for (int kc = 0; kc < 8; ++kc) {
          const int kb = kc * 4 + q;
          const s16x8 af = *(const s16x8*)(aLb + rE * 256 + (((kb & 24) | ((kb ^ re8) & 7)) << 3));
          const s16x8 bfr = *(const s16x8*)(smem + EXLo + (njo + r) * 256 +
                                            (((kb & 24) | ((kb ^ rx) & 7)) << 3));
          eacc[h] = MFMA16(af, bfr, eacc[h]);
        }
      }
      SCHED_FENCE(); WAIT_LGKM(); BAR(); SCHED_FENCE();
    }
  }

  // write partial [nchunk][8192][32]
  #pragma unroll
  for (int h = 0; h < 2; ++h) {
    const int rb = r0 + h * 128 + (w & 7) * 16 + q * 4;
    const int cls = (w >> 3) * 16 + r;
    #pragma unroll
    for (int t = 0; t < 4; ++t)
      partial[((size_t)nchunk * 8192 + rb + t) * 32 + cls] = eacc[h][t];
  }
}

// ---------------- reduce 16 partials, /b, clip ----------------
__global__ void k_reduce(const float* __restrict__ partial, const float* __restrict__ bvec,
                         float* __restrict__ out) {
  const int idx = blockIdx.x * 256 + threadIdx.x;  // 229376 total
  const int row = idx / 28, c = idx - row * 28;
  float s = 0.f;
  #pragma unroll
  for (int nc = 0; nc < 16; ++nc) s += partial[((size_t)nc * 8192 + row) * 32 + c];
  out[idx] = fminf(fmaxf(s / bvec[c], 0.f), 1.f);
}

extern "C" void kernel_launch(void* const* d_in, const int* in_sizes, int n_in,
                              void* d_out, int out_size, void* d_ws, size_t ws_size,
                              hipStream_t stream) {
  const float* features    = (const float*)d_in[0];  // [8192,1024]
  const float* ex_features = (const float*)d_in[1];  // [16384,1024]
  const float* g_w         = (const float*)d_in[2];  // [512,1024]
  const float* g_b         = (const float*)d_in[3];  // [512]
  const float* ex_classes  = (const float*)d_in[4];  // [16384,28]
  float* out = (float*)d_out;
  char* ws = (char*)d_ws;

  unsigned short* featbf = (unsigned short*)(ws + 0);
  unsigned short* exbf   = (unsigned short*)(ws + 16777216);
  unsigned short* fnall  = (unsigned short*)(ws + 0);
  float* fall            = (float*)(ws + 50331648);
  float* partial         = (float*)(ws + 50331648);
  unsigned short* gwbf   = (unsigned short*)(ws + 100663296);
  unsigned short* excT   = (unsigned short*)(ws + 101711872);
  float* bvec            = (float*)(ws + 102760448);

  k_cast_bf16<<<2048, 256, 0, stream>>>(features, featbf, 8192 * 1024 / 4);
  k_cast_bf16<<<2048, 256, 0, stream>>>(ex_features, exbf, 16384 * 1024 / 4);
  k_cast_bf16<<<512, 256, 0, stream>>>(g_w, gwbf, 512 * 1024 / 4);
  k_excT<<<32, 256, 0, stream>>>(ex_classes, excT, bvec);
  k_proj<<<dim3(96, 4), 512, 0, stream>>>(featbf, exbf, gwbf, g_b, fall);
  k_norm<<<6144, 256, 0, stream>>>(fall, fnall);
  k_fused<<<dim3(32, 16), 1024, 0, stream>>>(fnall, excT, partial);
  k_reduce<<<896, 256, 0, stream>>>(partial, bvec, out);
}

// Round 15
// 250.582 us; speedup vs baseline: 2.2229x; 2.2229x over previous
//
#include <hip/hip_runtime.h>
#include <stdint.h>

typedef __attribute__((ext_vector_type(4))) float f32x4;
typedef __attribute__((ext_vector_type(8))) short s16x8;

#define MFMA16(A, B, C) __builtin_amdgcn_mfma_f32_16x16x32_bf16(A, B, C, 0, 0, 0)
#define WAIT_VM(N) asm volatile("s_waitcnt vmcnt(" #N ")" ::: "memory")
#define WAIT_LGKM() asm volatile("s_waitcnt lgkmcnt(0)" ::: "memory")
#define BAR() __builtin_amdgcn_s_barrier()
#define SCHED_FENCE() __builtin_amdgcn_sched_barrier(0)
#define SP1() __builtin_amdgcn_s_setprio(1)
#define SP0() __builtin_amdgcn_s_setprio(0)

__device__ __forceinline__ unsigned short f2bf(float x) {
  union { float f; unsigned u; } v; v.f = x;
  return (unsigned short)((v.u + 0x7fffu + ((v.u >> 16) & 1u)) >> 16);
}

// ---------------- cast f32 -> bf16, 4 elems/thread ----------------
__global__ void k_cast_bf16(const float* __restrict__ in, unsigned short* __restrict__ out, int n4) {
  int i = blockIdx.x * blockDim.x + threadIdx.x;
  const int stride = gridDim.x * blockDim.x;
  for (; i < n4; i += stride) {
    const float4 v = ((const float4*)in)[i];
    ushort4 o;
    o.x = f2bf(v.x); o.y = f2bf(v.y); o.z = f2bf(v.z); o.w = f2bf(v.w);
    ((ushort4*)out)[i] = o;
  }
}

// ---------------- exc [16384][28] -> excT bf16 [32][16384] (rows 28..31 = 0) + b[28] ----------------
__global__ void k_excT(const float* __restrict__ exc, unsigned short* __restrict__ excT,
                       float* __restrict__ bvec) {
  const int c = blockIdx.x;        // 0..31
  const int tid = threadIdx.x;     // 256
  float sum = 0.f;
  for (int j = tid; j < 16384; j += 256) {
    const float v = (c < 28) ? exc[(size_t)j * 28 + c] : 0.f;
    excT[(size_t)c * 16384 + j] = f2bf(v);
    sum += v;
  }
  #pragma unroll
  for (int o = 32; o; o >>= 1) sum += __shfl_down(sum, o, 64);
  __shared__ float wsum[4];
  if ((tid & 63) == 0) wsum[tid >> 6] = sum;
  __syncthreads();
  if (tid == 0 && c < 28) bvec[c] = fmaxf(wsum[0] + wsum[1] + wsum[2] + wsum[3], 1.0f);
}

// ================= k_proj (unchanged working engine) =================
__device__ __forceinline__ void stage_a(const unsigned short* __restrict__ src, int ld,
                                        unsigned short* smem, int dsoff, int w, int offsrc) {
  #pragma unroll
  for (int c = 0; c < 4; ++c)
    __builtin_amdgcn_global_load_lds(
        (const __attribute__((address_space(1))) unsigned int*)(src + offsrc + c * 64 * ld),
        (__attribute__((address_space(3))) unsigned int*)(smem + dsoff + c * 4096 + w * 512),
        16, 0, 0);
}
__device__ __forceinline__ void stage_b(const unsigned short* __restrict__ src, int ld,
                                        unsigned short* smem, int dsoff, int w, int offsrc) {
  #pragma unroll
  for (int c = 0; c < 2; ++c)
    __builtin_amdgcn_global_load_lds(
        (const __attribute__((address_space(1))) unsigned int*)(src + offsrc + c * 64 * ld),
        (__attribute__((address_space(3))) unsigned int*)(smem + dsoff + c * 4096 + w * 512),
        16, 0, 0);
}

__device__ __forceinline__ void mma_step_p(const unsigned short* smem, int ao, int bo,
                                           int wr, int wc, int r, int q, f32x4 acc[8][2]) {
  const int rx = r & 7;
  #pragma unroll
  for (int ks = 0; ks < 2; ++ks) {
    const int sb = ((ks * 4 + q) ^ rx) << 3;
    s16x8 bf[2];
    #pragma unroll
    for (int j = 0; j < 2; ++j)
      bf[j] = *(const s16x8*)(smem + bo + (wc * 32 + j * 16 + r) * 64 + sb);
    #pragma unroll
    for (int i = 0; i < 8; ++i) {
      const s16x8 af = *(const s16x8*)(smem + ao + (wr * 128 + i * 16 + r) * 64 + sb);
      #pragma unroll
      for (int j = 0; j < 2; ++j)
        acc[i][j] = MFMA16(af, bf[j], acc[i][j]);
    }
  }
}

#define PA0 0
#define PB0 16384
#define PA1 24576
#define PB1 40960

__global__ __launch_bounds__(512, 2) void k_proj(const unsigned short* __restrict__ featbf,
                                                 const unsigned short* __restrict__ exbf,
                                                 const unsigned short* __restrict__ gwbf,
                                                 const float* __restrict__ gb,
                                                 float* __restrict__ fall) {
  __shared__ __align__(16) unsigned short smem[49152];  // 96 KB
  const int tid = threadIdx.x, w = tid >> 6, lane = tid & 63;
  const int wr = w >> 2, wc = w & 3, r = lane & 15, q = lane >> 4;
  const int offsrc = (w * 8 + (lane >> 3)) * 1024 + (((lane & 7) ^ (lane >> 3)) << 3);
  const int m0 = blockIdx.x * 256;
  const int n0 = blockIdx.y * 128;
  const unsigned short* Asrc = (m0 < 8192) ? (featbf + (size_t)m0 * 1024)
                                           : (exbf + (size_t)(m0 - 8192) * 1024);
  const unsigned short* Bsrc = gwbf + (size_t)n0 * 1024;
  f32x4 acc[8][2];
  #pragma unroll
  for (int i = 0; i < 8; ++i)
    #pragma unroll
    for (int j = 0; j < 2; ++j) acc[i][j] = {0.f, 0.f, 0.f, 0.f};

  stage_a(Asrc, 1024, smem, PA0, w, offsrc);
  stage_b(Bsrc, 1024, smem, PB0, w, offsrc);
  for (int t = 0; t < 15; ++t) {
    const int na = ((t + 1) & 1) ? PA1 : PA0, nbb = ((t + 1) & 1) ? PB1 : PB0;
    stage_a(Asrc + (t + 1) * 64, 1024, smem, na, w, offsrc);
    stage_b(Bsrc + (t + 1) * 64, 1024, smem, nbb, w, offsrc);
    WAIT_VM(6);
    BAR();
    mma_step_p(smem, (t & 1) ? PA1 : PA0, (t & 1) ? PB1 : PB0, wr, wc, r, q, acc);
    WAIT_LGKM();
    BAR();
  }
  WAIT_VM(0);
  BAR();
  mma_step_p(smem, PA1, PB1, wr, wc, r, q, acc);

  #pragma unroll
  for (int j = 0; j < 2; ++j) {
    const int col = n0 + wc * 32 + j * 16 + r;
    const float bias = gb[col];
    #pragma unroll
    for (int i = 0; i < 8; ++i) {
      const int row0 = m0 + wr * 128 + i * 16 + q * 4;
      #pragma unroll
      for (int t = 0; t < 4; ++t)
        fall[(size_t)(row0 + t) * 512 + col] = acc[i][j][t] + bias;
    }
  }
}

// ---------------- normalize rows of f_all (512) -> bf16 fn_all ----------------
__global__ __launch_bounds__(256) void k_norm(const float* __restrict__ fall,
                                              unsigned short* __restrict__ fn) {
  const int row = blockIdx.x * 4 + (threadIdx.x >> 6);
  const int lane = threadIdx.x & 63;
  const float4* p = (const float4*)(fall + (size_t)row * 512) + lane * 2;
  const float4 v0 = p[0], v1 = p[1];
  float ss = v0.x * v0.x + v0.y * v0.y + v0.z * v0.z + v0.w * v0.w
           + v1.x * v1.x + v1.y * v1.y + v1.z * v1.z + v1.w * v1.w;
  #pragma unroll
  for (int o = 32; o; o >>= 1) ss += __shfl_xor(ss, o, 64);
  const float sc = 1.0f / fmaxf(sqrtf(ss), 1e-12f);
  ushort4 o0, o1;
  o0.x = f2bf(v0.x * sc); o0.y = f2bf(v0.y * sc); o0.z = f2bf(v0.z * sc); o0.w = f2bf(v0.w * sc);
  o1.x = f2bf(v1.x * sc); o1.y = f2bf(v1.y * sc); o1.z = f2bf(v1.z * sc); o1.w = f2bf(v1.w * sc);
  ushort4* qo = (ushort4*)(fn + (size_t)row * 512) + lane * 2;
  qo[0] = o0; qo[1] = o1;
}

// ===== k_fused: BK=32, hoisted-read two-barrier phase (m201 pattern), swizzled staging =====
// LDS (shorts): buf0 @0, buf1 @16384 (each: A[256][32] @0 | B[256][32] @8192),
// excT [32][256] @32768, aL [128][256] @40960. Total 73728 shorts = 144 KB.
// Staging swizzle: LDS[row][blk] = G[row][blk ^ ((row>>1)&3)]; read koff = (q^((r>>1)&3))*8.
#define BUF 16384
#define EXLo 32768
#define ALo 40960

__device__ __forceinline__ void stage_p(const unsigned short* __restrict__ src,
                                        unsigned short* smem, int dsoff, int tid) {
  const int row = tid >> 2;
  const int scb = (tid & 3) ^ ((tid >> 3) & 3);
  const unsigned short* g = src + (size_t)row * 512 + scb * 8;
  __builtin_amdgcn_global_load_lds(
      (const __attribute__((address_space(1))) unsigned int*)g,
      (__attribute__((address_space(3))) unsigned int*)(smem + dsoff + tid * 8), 16, 0, 0);
}

__device__ __forceinline__ void stage_exc(const unsigned short* __restrict__ excTg, int c0,
                                          unsigned short* smem, int tid) {
  const int row = tid >> 5, b = tid & 31;
  const int sb = ((b & 24) | ((b ^ (row & 7)) & 7)) << 3;
  const unsigned short* g = excTg + (size_t)row * 16384 + c0 + sb;
  __builtin_amdgcn_global_load_lds(
      (const __attribute__((address_space(1))) unsigned int*)g,
      (__attribute__((address_space(3))) unsigned int*)(smem + EXLo + tid * 8), 16, 0, 0);
  __builtin_amdgcn_global_load_lds(
      (const __attribute__((address_space(1))) unsigned int*)(g + 16 * 16384),
      (__attribute__((address_space(3))) unsigned int*)(smem + EXLo + 4096 + tid * 8), 16, 0, 0);
}

__global__ __launch_bounds__(512, 2) void k_fused(const unsigned short* __restrict__ fnall,
                                                  const unsigned short* __restrict__ excT,
                                                  float* __restrict__ partial) {
  __shared__ __align__(16) unsigned short smem[73728];  // 144 KB
  const int tid = threadIdx.x, w = tid >> 6, lane = tid & 63;
  const int wr = w >> 2, wc = w & 3, r = lane & 15, q = lane >> 4, rx = r & 7;
  const int koff = (q ^ ((r >> 1) & 3)) << 3;
  const int r0 = blockIdx.x * 256;     // 32 M-tiles
  const int nchunk = blockIdx.y;       // 16 chunks x 4 j-tiles of 256
  const unsigned short* Abase = fnall + (size_t)r0 * 512;
  const unsigned short* Ebase = fnall + (size_t)8192 * 512;
  unsigned short* aLb = smem + ALo;

  f32x4 acc[2][2][4][2];               // [MH][NH][fi][fj]
  f32x4 eacc[2][2];
  #pragma unroll
  for (int a = 0; a < 2; ++a)
    #pragma unroll
    for (int b = 0; b < 2; ++b) eacc[a][b] = {0.f, 0.f, 0.f, 0.f};

  // prologue: jt0 tile0 -> buf0; certify before loop (hoisted reads need it)
  {
    const unsigned short* Bp = Ebase + (size_t)(nchunk * 4) * 256 * 512;
    stage_p(Bp, smem, 8192, tid);
    stage_p(Bp + 128 * 512, smem, 12288, tid);
    stage_p(Abase, smem, 0, tid);
    stage_p(Abase + 128 * 512, smem, 4096, tid);
    WAIT_VM(0);
    BAR(); SCHED_FENCE();
  }

  for (int jt = 0; jt < 4; ++jt) {
    const int c0 = (nchunk * 4 + jt) * 256;
    const unsigned short* Bsrc = Ebase + (size_t)c0 * 512;
    #pragma unroll
    for (int a = 0; a < 2; ++a)
      #pragma unroll
      for (int b = 0; b < 2; ++b)
        #pragma unroll
        for (int fi = 0; fi < 4; ++fi)
          #pragma unroll
          for (int fj = 0; fj < 2; ++fj) acc[a][b][fi][fj] = {0.f, 0.f, 0.f, 0.f};

    for (int tk = 0; tk < 16; ++tk) {
      const int bufR = (tk & 1) * BUF, bufW = bufR ^ BUF;
      // ---- hoisted frag reads: B (4) + A-MH0 (4); bufR certified at previous barrier
      s16x8 bf[2][2], af[4];
      {
        const unsigned short* Bb = smem + bufR + 8192 + (wc * 32 + r) * 32 + koff;
        #pragma unroll
        for (int nh = 0; nh < 2; ++nh)
          #pragma unroll
          for (int fj = 0; fj < 2; ++fj)
            bf[nh][fj] = *(const s16x8*)(Bb + (nh * 128 + fj * 16) * 32);
        const unsigned short* Ab0 = smem + bufR + (wr * 64 + r) * 32 + koff;
        #pragma unroll
        for (int fi = 0; fi < 4; ++fi)
          af[fi] = *(const s16x8*)(Ab0 + fi * 512);
      }
      // ---- stage tk+1 (or exc [+ next-jt tile0]) into bufW
      if (tk < 15) {
        const unsigned short* An = Abase + (tk + 1) * 32;
        const unsigned short* Bn = Bsrc + (tk + 1) * 32;
        stage_p(Bn, smem, bufW + 8192, tid);
        stage_p(Bn + 128 * 512, smem, bufW + 12288, tid);
        stage_p(An, smem, bufW + 0, tid);
        stage_p(An + 128 * 512, smem, bufW + 4096, tid);
      } else {
        stage_exc(excT, c0, smem, tid);          // exc FIRST (retired by vm(4) at BAR2)
        if (jt < 3) {
          const unsigned short* Bn = Ebase + (size_t)(c0 + 256) * 512;
          stage_p(Bn, smem, bufW + 8192, tid);
          stage_p(Bn + 128 * 512, smem, bufW + 12288, tid);
          stage_p(Abase, smem, bufW + 0, tid);
          stage_p(Abase + 128 * 512, smem, bufW + 4096, tid);
        }
      }
      SCHED_FENCE();
      BAR();                                     // BAR1: read latency hides under arrival
      WAIT_LGKM(); SCHED_FENCE();
      SP1();
      #pragma unroll
      for (int fi = 0; fi < 4; ++fi)             // MH0: 16 MFMA from held frags
        #pragma unroll
        for (int nh = 0; nh < 2; ++nh)
          #pragma unroll
          for (int fj = 0; fj < 2; ++fj)
            acc[0][nh][fi][fj] = MFMA16(af[fi], bf[nh][fj], acc[0][nh][fi][fj]);
      SP0();
      {                                          // read A-MH1 (reuse af regs)
        const unsigned short* Ab1 = smem + bufR + ((128 + wr * 64 + r) * 32) + koff;
        #pragma unroll
        for (int fi = 0; fi < 4; ++fi)
          af[fi] = *(const s16x8*)(Ab1 + fi * 512);
      }
      WAIT_LGKM(); SCHED_FENCE();
      SP1();
      #pragma unroll
      for (int fi = 0; fi < 4; ++fi)             // MH1: 16 MFMA
        #pragma unroll
        for (int nh = 0; nh < 2; ++nh)
          #pragma unroll
          for (int fj = 0; fj < 2; ++fj)
            acc[1][nh][fi][fj] = MFMA16(af[fi], bf[nh][fj], acc[1][nh][fi][fj]);
      SP0();
      SCHED_FENCE();
      if (tk < 15) { WAIT_VM(0); }               // staged ~500cy ago -> cheap drain
      else if (jt < 3) { WAIT_VM(4); }           // retire exc; next-jt panels keep flying
      else { WAIT_VM(0); }
      BAR(); SCHED_FENCE();                      // BAR2: bufW certified; bufR free
    }

    // ---- echo: a = s^3 via aL; exc already certified at tk15's BAR2
    #pragma unroll
    for (int h = 0; h < 2; ++h) {
      #pragma unroll
      for (int nh = 0; nh < 2; ++nh)
        #pragma unroll
        for (int fi = 0; fi < 4; ++fi)
          #pragma unroll
          for (int fj = 0; fj < 2; ++fj) {
            const int colc = nh * 128 + wc * 32 + fj * 16 + r;
            const int cb = colc >> 3, cl = colc & 7;
            #pragma unroll
            for (int t2 = 0; t2 < 4; ++t2) {
              const int row = wr * 64 + fi * 16 + q * 4 + t2;
              const float v = acc[h][nh][fi][fj][t2];
              aLb[row * 256 + ((((cb & 24) | ((cb ^ (row & 7)) & 7)) << 3) | cl)] = f2bf(v * v * v);
            }
          }
      SCHED_FENCE(); WAIT_LGKM(); BAR(); SCHED_FENCE();
      // echo MFMA (16x16x32): wave w owns rows w*16..+15 of this half; K=256, N=32
      {
        const int rE = w * 16 + r;
        const int re8 = rE & 7;
        #pragma unroll
        for (int kc = 0; kc < 8; ++kc) {
          const int kb = kc * 4 + q;
          const s16x8 af = *(const s16x8*)(aLb + rE * 256 + (((kb & 24) | ((kb ^ re8) & 7)) << 3));
          #pragma unroll
          for (int nj = 0; nj < 2; ++nj) {
            const s16x8 bfr = *(const s16x8*)(smem + EXLo + (nj * 16 + r) * 256 +
                                              (((kb & 24) | ((kb ^ rx) & 7)) << 3));
            eacc[h][nj] = MFMA16(af, bfr, eacc[h][nj]);
          }
        }
      }
      SCHED_FENCE(); WAIT_LGKM();
      if (h == 1) { WAIT_VM(0); }                // next-jt panels certified for tk=0 reads
      BAR(); SCHED_FENCE();
    }
  }

  // write partial [nchunk][8192][32]
  #pragma unroll
  for (int h = 0; h < 2; ++h)
    #pragma unroll
    for (int nj = 0; nj < 2; ++nj) {
      const int rb = r0 + h * 128 + w * 16 + q * 4;
      const int cls = nj * 16 + r;
      #pragma unroll
      for (int t = 0; t < 4; ++t)
        partial[((size_t)nchunk * 8192 + rb + t) * 32 + cls] = eacc[h][nj][t];
    }
}

// ---------------- reduce 16 partials, /b, clip ----------------
__global__ void k_reduce(const float* __restrict__ partial, const float* __restrict__ bvec,
                         float* __restrict__ out) {
  const int idx = blockIdx.x * 256 + threadIdx.x;  // 229376 total
  const int row = idx / 28, c = idx - row * 28;
  float s = 0.f;
  #pragma unroll
  for (int nc = 0; nc < 16; ++nc) s += partial[((size_t)nc * 8192 + row) * 32 + c];
  out[idx] = fminf(fmaxf(s / bvec[c], 0.f), 1.f);
}

extern "C" void kernel_launch(void* const* d_in, const int* in_sizes, int n_in,
                              void* d_out, int out_size, void* d_ws, size_t ws_size,
                              hipStream_t stream) {
  const float* features    = (const float*)d_in[0];  // [8192,1024]
  const float* ex_features = (const float*)d_in[1];  // [16384,1024]
  const float* g_w         = (const float*)d_in[2];  // [512,1024]
  const float* g_b         = (const float*)d_in[3];  // [512]
  const float* ex_classes  = (const float*)d_in[4];  // [16384,28]
  float* out = (float*)d_out;
  char* ws = (char*)d_ws;

  unsigned short* featbf = (unsigned short*)(ws + 0);
  unsigned short* exbf   = (unsigned short*)(ws + 16777216);
  unsigned short* fnall  = (unsigned short*)(ws + 0);
  float* fall            = (float*)(ws + 50331648);
  float* partial         = (float*)(ws + 50331648);
  unsigned short* gwbf   = (unsigned short*)(ws + 100663296);
  unsigned short* excT   = (unsigned short*)(ws + 101711872);
  float* bvec            = (float*)(ws + 102760448);

  k_cast_bf16<<<2048, 256, 0, stream>>>(features, featbf, 8192 * 1024 / 4);
  k_cast_bf16<<<2048, 256, 0, stream>>>(ex_features, exbf, 16384 * 1024 / 4);
  k_cast_bf16<<<512, 256, 0, stream>>>(g_w, gwbf, 512 * 1024 / 4);
  k_excT<<<32, 256, 0, stream>>>(ex_classes, excT, bvec);
  k_proj<<<dim3(96, 4), 512, 0, stream>>>(featbf, exbf, gwbf, g_b, fall);
  k_norm<<<6144, 256, 0, stream>>>(fall, fnall);
  k_fused<<<dim3(32, 16), 512, 0, stream>>>(fnall, excT, partial);
  k_reduce<<<896, 256, 0, stream>>>(partial, bvec, out);
}